// Round 7
// baseline (1005.001 us; speedup 1.0000x reference)
//
#include <hip/hip_runtime.h>

// ConvGRU, fp16 MFMA implicit GEMM.
// R7 = R6 cell code with the two pair-roles FUSED INTO ONE WG:
//   stage {hs0=h0'(t), hs1=h1(t), xt=x(t+1)} once -> compute L1(t) ->
//   barrier -> compute L0(t+1) REUSING staged hs0 (no second staging, no
//   second h0' fetch). 512 WGs x 512 thr = exactly 2 WG/CU, 1 round.
// Why (R6 counters): pair dispatch = 38MB traffic @ ~600GB/s ~= 64us; h0r
// fetched twice (once per role) and each role paid its own staging stall.
// Schedule (dependency-depth-optimal, 17 dispatches):
//   [L0(0)], 15x fused[L1(t);L0(t+1)], [L1(15)+NCHW emit].
// States fp16 NHWC padded planes [B][130][130][32], 1-px zero halo,
// ping-pong buffered. Stage tile 12x36 (2-px halo) via global_load_lds;
// clamped rows/cols land in the zero halo ring == SAME-pad value.

#define HH 128
#define PH 130
#define HW 16384
#define BB 8
#define TT 16

typedef _Float16 f16x8 __attribute__((ext_vector_type(8)));
typedef float f32x4 __attribute__((ext_vector_type(4)));
typedef unsigned int u32x4 __attribute__((ext_vector_type(4)));

__device__ __forceinline__ unsigned short f2h(float x){
    return __builtin_bit_cast(unsigned short, (_Float16)x);
}
__device__ __forceinline__ float h2f(unsigned short u){
    return (float)__builtin_bit_cast(_Float16, u);
}
__device__ __forceinline__ f16x8 ld_frag(const unsigned short* p){
    u32x4 v = *(const u32x4*)p;
    return __builtin_bit_cast(f16x8, v);
}
__device__ __forceinline__ f16x8 lds_frag_w(const unsigned short* base, int spix, int q){
    u32x4 v = *(const u32x4*)(base + spix * 32 + q * 8);
    return __builtin_bit_cast(f16x8, v);
}
__device__ __forceinline__ float sigmoid_f(float a){ return 1.0f / (1.0f + __expf(-a)); }
__device__ __forceinline__ float tanh_f(float a){ float e2 = __expf(2.0f * a); return 1.0f - 2.0f / (e2 + 1.0f); }

// LDS block: 2 stage planes 12x36x32 fp16 + rh 10x34x32 fp16 + x 12x37 fp32
struct SmemT {
    unsigned short hs[2][13824];   // 55,296 B
    unsigned short rh[10880];      // 21,760 B (also out-transpose scratch)
    float xt[444];                 //  1,776 B   => 78,832 B total
};

// halo enumeration for 10x34 gates region: 84 px (rows 0,9 full; rows 1..8
// cols 0,33) as 6 16-px M-tiles; s>83 clamps (benign same-value dups).
__device__ __forceinline__ void halo_rc10(int s, int& gr, int& gc){
    s = s > 83 ? 83 : s;
    if (s < 34)      { gr = 0;            gc = s;      }
    else if (s < 68) { gr = 9;            gc = s - 34; }
    else if (s < 76) { gr = 1 + (s - 68); gc = 0;      }
    else             { gr = 1 + (s - 76); gc = 33;     }
}

// im2col x fragment for gates pixel (gr,gc); xt stride 37, origin R0-2,C0-2
__device__ __forceinline__ f16x8 x_im2col(const float* xt, int gr, int gc, int q){
    f16x8 v;
#pragma unroll
    for (int j = 0; j < 8; ++j) {
        int k = q * 8 + j;
        float f = 0.0f;
        if (k < 9) f = xt[(gr + k / 3) * 37 + gc + k % 3];
        v[j] = (_Float16)f;
    }
    return v;
}

// ---- async DMA staging: 12x36 tile = 432 px * 4 chunks = 1728 = 27*64 ----
__device__ __forceinline__ void stage_plane12(unsigned short* slot,
    const unsigned short* __restrict__ g, int b, int pr0, int pc0)
{
    const int wv = threadIdx.x >> 6, lane = threadIdx.x & 63;
    for (int k = wv; k < 27; k += 8) {
        int chunk = k * 64 + lane;
        int pix = chunk >> 2, part = chunk & 3;
        int r = pix / 36, c = pix - r * 36;
        int pr = pr0 + r; pr = pr < 0 ? 0 : (pr > 129 ? 129 : pr);
        int pc = pc0 + c; pc = pc < 0 ? 0 : (pc > 129 ? 129 : pc);
        const unsigned short* ga = g + ((long)((b * PH + pr) * PH + pc) * 32 + part * 8);
        __builtin_amdgcn_global_load_lds(
            (const __attribute__((address_space(1))) unsigned int*)ga,
            (__attribute__((address_space(3))) unsigned int*)(slot + k * 512),
            16, 0, 0);
    }
}

// stage x(t) 12x37 fp32 tile (scalar loads; done BEFORE DMA issue)
__device__ __forceinline__ void stage_x12(float* xt, const float* __restrict__ seq,
                                          int b, int t, int R0, int C0)
{
    if (threadIdx.x < 444) {
        int p = threadIdx.x;
        int r = p / 37, c = p - r * 37;
        int ir = R0 - 2 + r, ic = C0 - 2 + c;
        float v = 0.0f;
        if (ir >= 0 && ir < HH && ic >= 0 && ic < HH)
            v = seq[((long)b * TT + t) * HW + ir * HH + ic];
        xt[p] = v;
    }
}

// ---- weight prep: [cout][cin_tot][9] fp32 -> [step][cout][32] fp16 ----
__global__ void prep_w(const float* __restrict__ w, unsigned short* __restrict__ wf,
                       int CO, int CIT, int NSTEP, int xmode)
{
    int idx = blockIdx.x * 256 + threadIdx.x;
    int total = NSTEP * CO * 32;
    if (idx >= total) return;
    int kk = idx & 31;
    int t  = idx >> 5;
    int co = t % CO;
    int s  = t / CO;
    float v = 0.0f;
    if (xmode && s == NSTEP - 1) {
        if (kk < 9) v = w[(co * CIT + 0) * 9 + kk];
    } else {
        int tap = s % 9;
        int cin = (s / 9) * 32 + kk + (xmode ? 1 : 0);
        v = w[(co * CIT + cin) * 9 + tap];
    }
    wf[idx] = f2h(v);
}

// ---- cell compute (staging assumed done; R6-verified arithmetic) ----
// L=0: reads sm.hs[0] (h_old) + sm.xt. L=1: reads sm.hs[0] (x-part plane)
// + sm.hs[1] (h_old). EMIT: write NCHW fp32 out instead of Hout.
template<int L, int EMIT>
__device__ __forceinline__ void cell_compute(SmemT& sm,
    unsigned short* __restrict__ Hout,
    const unsigned short* __restrict__ Wg, const float* __restrict__ bg,
    const unsigned short* __restrict__ Wc, const float* __restrict__ bc,
    float* __restrict__ out, int b, int R0, int C0)
{
    constexpr int KG = (L == 0) ? 10 : 18;
    constexpr int KC = (L == 0) ? 10 : 18;

    const int wv = threadIdx.x >> 6, lane = threadIdx.x & 63;
    const int m16 = lane & 15, q = lane >> 4;
    const unsigned short* hp = (L == 0) ? sm.hs[0] : sm.hs[1];

    // ---- phase 1: gates conv on 10x34 (16 interior tiles aligned with the
    // cand fragment layout + 6 halo tiles on waves 2..7; halo = r-couts only)
    const bool HASH = (wv >= 2);
    int hgr = 0, hgc = 0;
    halo_rc10((wv - 2) * 16 + m16, hgr, hgc);

    f32x4 gI[2][4];
    f32x4 gH[2];
#pragma unroll
    for (int ng = 0; ng < 4; ++ng) {
        float bv = bg[ng * 16 + m16];
#pragma unroll
        for (int mg = 0; mg < 2; ++mg) gI[mg][ng] = f32x4{bv, bv, bv, bv};
        if (ng < 2) gH[ng] = f32x4{bv, bv, bv, bv};
    }

    // register double-buffered B-fragments: load s+1 before MFMA(s)
    f16x8 Bc[4];
#pragma unroll
    for (int ng = 0; ng < 4; ++ng)
        Bc[ng] = ld_frag(Wg + (ng * 16 + m16) * 32 + q * 8);

#pragma unroll
    for (int s = 0; s < KG; ++s) {
        f16x8 Bn[4];
        if (s + 1 < KG) {
#pragma unroll
            for (int ng = 0; ng < 4; ++ng)
                Bn[ng] = ld_frag(Wg + ((s + 1) * 64 + ng * 16 + m16) * 32 + q * 8);
        }
        f16x8 AI[2], AH;
        if (L == 0 && s == 9) {
#pragma unroll
            for (int mg = 0; mg < 2; ++mg)
                AI[mg] = x_im2col(sm.xt, wv + 1, mg * 16 + 1 + m16, q);
            AH = x_im2col(sm.xt, hgr, hgc, q);
        } else {
            const int tap = (L == 0) ? s : (s % 9);
            const unsigned short* pl = (L == 1 && s >= 9) ? sm.hs[1] : sm.hs[0];
#pragma unroll
            for (int mg = 0; mg < 2; ++mg)
                AI[mg] = lds_frag_w(pl, (wv + 1 + tap / 3) * 36 + mg * 16 + 1 + m16 + tap % 3, q);
            AH = lds_frag_w(pl, (hgr + tap / 3) * 36 + hgc + tap % 3, q);
        }
#pragma unroll
        for (int mg = 0; mg < 2; ++mg)
#pragma unroll
            for (int ng = 0; ng < 4; ++ng)
                gI[mg][ng] = __builtin_amdgcn_mfma_f32_16x16x32_f16(AI[mg], Bc[ng], gI[mg][ng], 0, 0, 0);
        if (HASH) {
#pragma unroll
            for (int ng = 0; ng < 2; ++ng)
                gH[ng] = __builtin_amdgcn_mfma_f32_16x16x32_f16(AH, Bc[ng], gH[ng], 0, 0, 0);
        }
        if (s + 1 < KG) {
#pragma unroll
            for (int ng = 0; ng < 4; ++ng) Bc[ng] = Bn[ng];
        }
    }

    // gates epilogue. C layout: col(n)=lane&15, row(pixel)=q*4+rg.
    // Interior: r*h -> rh LDS; z -> packed f16x2 regs (thread-aligned with
    // the update epilogue). Halo: r*h only.
    unsigned int zpk[2][4];
#pragma unroll
    for (int mg = 0; mg < 2; ++mg)
#pragma unroll
        for (int rg = 0; rg < 4; ++rg) {
            int gr = wv + 1, gc = mg * 16 + 1 + q * 4 + rg;
            zpk[mg][rg] = (unsigned int)f2h(sigmoid_f(gI[mg][2][rg]))
                        | ((unsigned int)f2h(sigmoid_f(gI[mg][3][rg])) << 16);
#pragma unroll
            for (int ng = 0; ng < 2; ++ng) {
                int n = ng * 16 + m16;
                float rv = sigmoid_f(gI[mg][ng][rg]);
                float hv = h2f(hp[((gr + 1) * 36 + gc + 1) * 32 + n]);
                sm.rh[(gr * 34 + gc) * 32 + n] = f2h(rv * hv);
            }
        }
    if (HASH) {
#pragma unroll
        for (int rg = 0; rg < 4; ++rg) {
            int gr, gc; halo_rc10((wv - 2) * 16 + q * 4 + rg, gr, gc);
#pragma unroll
            for (int ng = 0; ng < 2; ++ng) {
                int n = ng * 16 + m16;
                float rv = sigmoid_f(gH[ng][rg]);
                float hv = h2f(hp[((gr + 1) * 36 + gc + 1) * 32 + n]);
                sm.rh[(gr * 34 + gc) * 32 + n] = f2h(rv * hv);
            }
        }
    }
    __syncthreads();

    // ---- phase 2: candidate conv on interior 8x32 (wave = 1 row, 2 m-tiles)
    f32x4 cacc[2][2];
#pragma unroll
    for (int mg = 0; mg < 2; ++mg)
#pragma unroll
        for (int ng = 0; ng < 2; ++ng) {
            float bv = bc[ng * 16 + m16];
            cacc[mg][ng] = f32x4{bv, bv, bv, bv};
        }
    f16x8 Cc[2];
#pragma unroll
    for (int ng = 0; ng < 2; ++ng)
        Cc[ng] = ld_frag(Wc + (ng * 16 + m16) * 32 + q * 8);
#pragma unroll
    for (int s = 0; s < KC; ++s) {
        f16x8 Cn[2];
        if (s + 1 < KC) {
#pragma unroll
            for (int ng = 0; ng < 2; ++ng)
                Cn[ng] = ld_frag(Wc + ((s + 1) * 32 + ng * 16 + m16) * 32 + q * 8);
        }
        f16x8 A2[2];
        if (L == 0 && s == 9) {
#pragma unroll
            for (int mg = 0; mg < 2; ++mg)
                A2[mg] = x_im2col(sm.xt, wv + 1, mg * 16 + 1 + m16, q);
        } else if (L == 1 && s < 9) {
#pragma unroll
            for (int mg = 0; mg < 2; ++mg)
                A2[mg] = lds_frag_w(sm.hs[0], (wv + 1 + s / 3) * 36 + mg * 16 + m16 + 1 + s % 3, q);
        } else {
            const int tap = (L == 0) ? s : (s - 9);
#pragma unroll
            for (int mg = 0; mg < 2; ++mg)
                A2[mg] = lds_frag_w(sm.rh, (wv + tap / 3) * 34 + mg * 16 + m16 + tap % 3, q);
        }
#pragma unroll
        for (int mg = 0; mg < 2; ++mg)
#pragma unroll
            for (int ng = 0; ng < 2; ++ng)
                cacc[mg][ng] = __builtin_amdgcn_mfma_f32_16x16x32_f16(A2[mg], Cc[ng], cacc[mg][ng], 0, 0, 0);
        if (s + 1 < KC) {
#pragma unroll
            for (int ng = 0; ng < 2; ++ng) Cc[ng] = Cn[ng];
        }
    }

    // ---- update epilogue: h' = (1-z)*h_old + z*tanh(n) ----
    unsigned short hvout[2][2][4];
#pragma unroll
    for (int mg = 0; mg < 2; ++mg)
#pragma unroll
        for (int ng = 0; ng < 2; ++ng)
#pragma unroll
            for (int rg = 0; rg < 4; ++rg) {
                int lcol = mg * 16 + q * 4 + rg;
                int n = ng * 16 + m16;
                float nv = tanh_f(cacc[mg][ng][rg]);
                float zz = h2f((unsigned short)(zpk[mg][rg] >> (ng * 16)));
                float ho = h2f(hp[((wv + 2) * 36 + lcol + 2) * 32 + n]);
                float hnew = (1.0f - zz) * ho + zz * nv;
                if (!EMIT) {
                    long psp = (long)(b * PH + R0 + wv + 1) * PH + (C0 + lcol + 1);
                    Hout[psp * 32 + n] = f2h(hnew);
                } else {
                    hvout[mg][ng][rg] = f2h(hnew);
                }
            }

    if (EMIT) {
        // NCHW out via LDS transpose; rh is dead after cand -> scratch.
        __syncthreads();
        unsigned short* scr = sm.rh;      // [8 rows][32 cols][32 ch]
#pragma unroll
        for (int mg = 0; mg < 2; ++mg)
#pragma unroll
            for (int ng = 0; ng < 2; ++ng)
#pragma unroll
                for (int rg = 0; rg < 4; ++rg)
                    scr[((wv * 32 + mg * 16 + q * 4 + rg) * 32) + ng * 16 + m16] = hvout[mg][ng][rg];
        __syncthreads();
        const int tid = threadIdx.x;
        const int rowid = tid >> 1, half = tid & 1;
        const int n = rowid >> 3, wr = rowid & 7;
        long obase = ((long)(b * 32 + n) * HH + (R0 + wr)) * HH + C0 + half * 16;
#pragma unroll
        for (int j = 0; j < 16; ++j)
            out[obase + j] = h2f(scr[(wr * 32 + half * 16 + j) * 32 + n]);
    }
}

// ---- solo L0 (t=0): stage h0 + x, compute ----
__global__ __launch_bounds__(512, 4)
void cell_l0(const unsigned short* __restrict__ Hin, unsigned short* __restrict__ Hout,
             const float* __restrict__ seq, int t,
             const unsigned short* __restrict__ Wg, const float* __restrict__ bg,
             const unsigned short* __restrict__ Wc, const float* __restrict__ bc)
{
    __shared__ __align__(16) SmemT sm;
    const int wg = blockIdx.x;
    const int b = wg >> 6, tr = (wg >> 2) & 15, tc = wg & 3;
    const int R0 = tr * 8, C0 = tc * 32;
    stage_x12(sm.xt, seq, b, t, R0, C0);
    stage_plane12(sm.hs[0], Hin, b, R0 - 1, C0 - 1);
    __syncthreads();
    cell_compute<0, 0>(sm, Hout, Wg, bg, Wc, bc, (float*)0, b, R0, C0);
}

// ---- fused pair: one WG = L1(t) then L0(t+1), sharing staged hs0 ----
__global__ __launch_bounds__(512, 4)
void fused_pair(const unsigned short* __restrict__ h1r, unsigned short* __restrict__ h1w,
                const unsigned short* __restrict__ h0r, unsigned short* __restrict__ h0w,
                const float* __restrict__ seq, int tnext,
                const unsigned short* __restrict__ WG0, const float* __restrict__ gb0,
                const unsigned short* __restrict__ WC0, const float* __restrict__ cb0,
                const unsigned short* __restrict__ WG1, const float* __restrict__ gb1,
                const unsigned short* __restrict__ WC1, const float* __restrict__ cb1)
{
    __shared__ __align__(16) SmemT sm;
    const int wg = blockIdx.x;
    const int b = wg >> 6, tr = (wg >> 2) & 15, tc = wg & 3;
    const int R0 = tr * 8, C0 = tc * 32;
    // stage x(t+1) first (its implicit vmcnt drain precedes DMA issue),
    // then both state planes via DMA; one barrier drains everything.
    stage_x12(sm.xt, seq, b, tnext, R0, C0);
    stage_plane12(sm.hs[0], h0r, b, R0 - 1, C0 - 1);   // h0'(t): x-part of L1, h-old of L0
    stage_plane12(sm.hs[1], h1r, b, R0 - 1, C0 - 1);   // h1(t): h-old of L1
    __syncthreads();
    // L1(t): h1' = cell1(h0'(t), h1(t))
    cell_compute<1, 0>(sm, h1w, WG1, gb1, WC1, cb1, (float*)0, b, R0, C0);
    __syncthreads();   // rh recycle: all L1 reads done before L0 writes rh
    // L0(t+1): h0' = cell0(x(t+1), h0'(t)) -- hs0 already staged!
    cell_compute<0, 0>(sm, h0w, WG0, gb0, WC0, cb0, (float*)0, b, R0, C0);
}

// ---- final L1(T-1) with inline NCHW emit ----
__global__ __launch_bounds__(512, 4)
void cell_l1_emit(const unsigned short* __restrict__ Hin,
                  const unsigned short* __restrict__ Xin,
                  const unsigned short* __restrict__ Wg, const float* __restrict__ bg,
                  const unsigned short* __restrict__ Wc, const float* __restrict__ bc,
                  float* __restrict__ out)
{
    __shared__ __align__(16) SmemT sm;
    const int wg = blockIdx.x;
    const int b = wg >> 6, tr = (wg >> 2) & 15, tc = wg & 3;
    const int R0 = tr * 8, C0 = tc * 32;
    stage_plane12(sm.hs[0], Xin, b, R0 - 1, C0 - 1);
    stage_plane12(sm.hs[1], Hin, b, R0 - 1, C0 - 1);
    __syncthreads();
    cell_compute<1, 1>(sm, (unsigned short*)0, Wg, bg, Wc, bc, out, b, R0, C0);
}

extern "C" void kernel_launch(void* const* d_in, const int* in_sizes, int n_in,
                              void* d_out, int out_size, void* d_ws, size_t ws_size,
                              hipStream_t stream)
{
    const float* seq = (const float*)d_in[0];
    const float* gw0 = (const float*)d_in[1];
    const float* gb0 = (const float*)d_in[2];
    const float* cw0 = (const float*)d_in[3];
    const float* cb0 = (const float*)d_in[4];
    const float* gw1 = (const float*)d_in[5];
    const float* gb1 = (const float*)d_in[6];
    const float* cw1 = (const float*)d_in[7];
    const float* cb1 = (const float*)d_in[8];
    float* out = (float*)d_out;

    const size_t NSP = (size_t)BB * PH * PH * 32;    // 4,326,400 fp16 per plane

    char* p = (char*)d_ws;
    unsigned short* S0A = (unsigned short*)p; p += NSP * 2;
    unsigned short* S0B = (unsigned short*)p; p += NSP * 2;
    unsigned short* S1A = (unsigned short*)p; p += NSP * 2;
    unsigned short* S1B = (unsigned short*)p; p += NSP * 2;
    unsigned short* WG0 = (unsigned short*)p; p += 20480 * 2;
    unsigned short* WC0 = (unsigned short*)p; p += 10240 * 2;
    unsigned short* WG1 = (unsigned short*)p; p += 36864 * 2;
    unsigned short* WC1 = (unsigned short*)p; p += 18432 * 2;

    // zero all 4 state planes (h=0 init + permanent zero halos), one span
    hipMemsetAsync(S0A, 0, 4 * NSP * 2, stream);

    prep_w<<<(10 * 64 * 32 + 255) / 256, 256, 0, stream>>>(gw0, WG0, 64, 33, 10, 1);
    prep_w<<<(10 * 32 * 32 + 255) / 256, 256, 0, stream>>>(cw0, WC0, 32, 33, 10, 1);
    prep_w<<<(18 * 64 * 32 + 255) / 256, 256, 0, stream>>>(gw1, WG1, 64, 64, 18, 0);
    prep_w<<<(18 * 32 * 32 + 255) / 256, 256, 0, stream>>>(cw1, WC1, 32, 64, 18, 0);

    dim3 grid(512, 1, 1), block(512);

    // t=0, layer 0: h0'(0) = cell0(x0, 0); reads S0A (zeros) writes S0B
    cell_l0<<<grid, block, 0, stream>>>(S0A, S0B, seq, 0, WG0, gb0, WC0, cb0);

    // fused pairs: dispatch k runs L1(k) then L0(k+1) in the same WG
    unsigned short *h0r = S0B, *h0w = S0A, *h1r = S1A, *h1w = S1B;
    for (int t = 0; t < TT - 1; ++t) {
        fused_pair<<<grid, block, 0, stream>>>(h1r, h1w, h0r, h0w, seq, t + 1,
                                               WG0, gb0, WC0, cb0,
                                               WG1, gb1, WC1, cb1);
        unsigned short* tmp;
        tmp = h0r; h0r = h0w; h0w = tmp;
        tmp = h1r; h1r = h1w; h1w = tmp;
    }
    // final: h1'(15) = cell1(h0'(15), h1'(14)), emits NCHW fp32 out
    cell_l1_emit<<<grid, block, 0, stream>>>(h1r, h0r, WG1, gb1, WC1, cb1, out);
}

// Round 8
// 1004.167 us; speedup vs baseline: 1.0008x; 1.0008x over previous
//
#include <hip/hip_runtime.h>

// ConvGRU, fp16 MFMA implicit GEMM.
// R8 = R6 (best: 967us; step_pair grid.z=2, 512thr, 8x32 tile, weight dbuf)
//      + LDS XOR-SWIZZLE on hs planes and rh (T2, rule #21 both-sides):
// R6 counters: SQ_LDS_BANK_CONFLICT 3.56M cy (9%/CU, serial on LDS pipe).
// Cause: frag reads at byte pix*64+q*16 -> bank-quad {q, pix&1} -> 8 lanes
// per quad = 8-way conflict on EVERY ds_read_b128 + epilogue scalar ops.
// Fix: involution on ushort idx  i ^= ((i>>6)&7)<<3  (byte bits4-6 ^= (pix>>1)&7):
// 16 consecutive pixels spread 2-per-quad = free. global_load_lds writes
// linearly -> staging pre-swizzles the GLOBAL source chunk (u ^= (u>>3)&7 in
// 16B units); all hs/rh reads+writes apply the same XOR. EMIT scratch stays
// linear (separate lifetime, self-consistent).
// Schedule: [L0(0)], 15x step_pair[L1(t) || L0(t+1)] (z roles), [L1(15)+emit].
// States fp16 NHWC padded planes [B][130][130][32], 1-px zero halo, ping-pong.
// Stage tile 12x36 (2-px halo) via global_load_lds; clamped rows/cols land in
// the zero halo ring == SAME-pad value.

#define HH 128
#define PH 130
#define HW 16384
#define BB 8
#define TT 16

typedef _Float16 f16x8 __attribute__((ext_vector_type(8)));
typedef float f32x4 __attribute__((ext_vector_type(4)));
typedef unsigned int u32x4 __attribute__((ext_vector_type(4)));

__device__ __forceinline__ unsigned short f2h(float x){
    return __builtin_bit_cast(unsigned short, (_Float16)x);
}
__device__ __forceinline__ float h2f(unsigned short u){
    return (float)__builtin_bit_cast(_Float16, u);
}
__device__ __forceinline__ f16x8 ld_frag(const unsigned short* p){
    u32x4 v = *(const u32x4*)p;
    return __builtin_bit_cast(f16x8, v);
}
// LDS XOR swizzle, ushort units: byte bits 4-6 ^= (pix>>1)&7. Involution.
__device__ __forceinline__ int swzus(int i){ return i ^ (((i >> 6) & 7) << 3); }
// swizzled fragment read: logical (pixel spix, ch octet q) of a [pix][32ch] buffer
__device__ __forceinline__ f16x8 lds_frag_s(const unsigned short* base, int spix, int q){
    int idx = swzus(spix * 32 + q * 8);
    u32x4 v = *(const u32x4*)(base + idx);
    return __builtin_bit_cast(f16x8, v);
}
__device__ __forceinline__ float sigmoid_f(float a){ return 1.0f / (1.0f + __expf(-a)); }
__device__ __forceinline__ float tanh_f(float a){ float e2 = __expf(2.0f * a); return 1.0f - 2.0f / (e2 + 1.0f); }

// LDS block: 2 stage planes 12x36x32 fp16 + rh 10x34x32 fp16 + x 12x37 fp32
struct SmemT {
    unsigned short hs[2][13824];   // 55,296 B (swizzled layout)
    unsigned short rh[10880];      // 21,760 B (swizzled; linear as EMIT scratch)
    float xt[444];                 //  1,776 B   => 78,832 B total
};

// halo enumeration for 10x34 gates region: 84 px (rows 0,9 full; rows 1..8
// cols 0,33) as 6 16-px M-tiles; s>83 clamps (benign same-value dups).
__device__ __forceinline__ void halo_rc10(int s, int& gr, int& gc){
    s = s > 83 ? 83 : s;
    if (s < 34)      { gr = 0;            gc = s;      }
    else if (s < 68) { gr = 9;            gc = s - 34; }
    else if (s < 76) { gr = 1 + (s - 68); gc = 0;      }
    else             { gr = 1 + (s - 76); gc = 33;     }
}

// im2col x fragment for gates pixel (gr,gc); xt stride 37, origin R0-2,C0-2
__device__ __forceinline__ f16x8 x_im2col(const float* xt, int gr, int gc, int q){
    f16x8 v;
#pragma unroll
    for (int j = 0; j < 8; ++j) {
        int k = q * 8 + j;
        float f = 0.0f;
        if (k < 9) f = xt[(gr + k / 3) * 37 + gc + k % 3];
        v[j] = (_Float16)f;
    }
    return v;
}

// ---- async DMA staging: 12x36 tile = 432 px * 4 chunks = 1728 = 27*64 ----
// LDS dest is linear (HW: base + lane*16B); the SOURCE chunk is pre-swizzled
// with the same involution the reads use: 16B-unit u -> u ^ ((u>>3)&7).
__device__ __forceinline__ void stage_plane12(unsigned short* slot,
    const unsigned short* __restrict__ g, int b, int pr0, int pc0)
{
    const int wv = threadIdx.x >> 6, lane = threadIdx.x & 63;
    for (int k = wv; k < 27; k += 8) {
        int u = k * 64 + lane;                 // LDS 16B-unit this lane fills
        int cch = u ^ ((u >> 3) & 7);          // global chunk that belongs there
        int pix = cch >> 2, part = cch & 3;
        int r = pix / 36, c = pix - r * 36;
        int pr = pr0 + r; pr = pr < 0 ? 0 : (pr > 129 ? 129 : pr);
        int pc = pc0 + c; pc = pc < 0 ? 0 : (pc > 129 ? 129 : pc);
        const unsigned short* ga = g + ((long)((b * PH + pr) * PH + pc) * 32 + part * 8);
        __builtin_amdgcn_global_load_lds(
            (const __attribute__((address_space(1))) unsigned int*)ga,
            (__attribute__((address_space(3))) unsigned int*)(slot + k * 512),
            16, 0, 0);
    }
}

// stage x(t) 12x37 fp32 tile (scalar loads)
__device__ __forceinline__ void stage_x12(float* xt, const float* __restrict__ seq,
                                          int b, int t, int R0, int C0)
{
    if (threadIdx.x < 444) {
        int p = threadIdx.x;
        int r = p / 37, c = p - r * 37;
        int ir = R0 - 2 + r, ic = C0 - 2 + c;
        float v = 0.0f;
        if (ir >= 0 && ir < HH && ic >= 0 && ic < HH)
            v = seq[((long)b * TT + t) * HW + ir * HH + ic];
        xt[p] = v;
    }
}

// ---- weight prep: [cout][cin_tot][9] fp32 -> [step][cout][32] fp16 ----
__global__ void prep_w(const float* __restrict__ w, unsigned short* __restrict__ wf,
                       int CO, int CIT, int NSTEP, int xmode)
{
    int idx = blockIdx.x * 256 + threadIdx.x;
    int total = NSTEP * CO * 32;
    if (idx >= total) return;
    int kk = idx & 31;
    int t  = idx >> 5;
    int co = t % CO;
    int s  = t / CO;
    float v = 0.0f;
    if (xmode && s == NSTEP - 1) {
        if (kk < 9) v = w[(co * CIT + 0) * 9 + kk];
    } else {
        int tap = s % 9;
        int cin = (s / 9) * 32 + kk + (xmode ? 1 : 0);
        v = w[(co * CIT + cin) * 9 + tap];
    }
    wf[idx] = f2h(v);
}

// ---- cell compute (staging done by caller; R6-verified arithmetic,
//      all hs/rh LDS accesses swizzle-wrapped) ----
template<int L, int EMIT>
__device__ __forceinline__ void cell_compute(SmemT& sm,
    unsigned short* __restrict__ Hout,
    const unsigned short* __restrict__ Wg, const float* __restrict__ bg,
    const unsigned short* __restrict__ Wc, const float* __restrict__ bc,
    float* __restrict__ out, int b, int R0, int C0)
{
    constexpr int KG = (L == 0) ? 10 : 18;
    constexpr int KC = (L == 0) ? 10 : 18;

    const int wv = threadIdx.x >> 6, lane = threadIdx.x & 63;
    const int m16 = lane & 15, q = lane >> 4;
    const unsigned short* hp = (L == 0) ? sm.hs[0] : sm.hs[1];

    // ---- phase 1: gates conv on 10x34 (16 interior tiles + 6 halo tiles on
    // waves 2..7; halo = r-couts only) ----
    const bool HASH = (wv >= 2);
    int hgr = 0, hgc = 0;
    halo_rc10((wv - 2) * 16 + m16, hgr, hgc);

    f32x4 gI[2][4];
    f32x4 gH[2];
#pragma unroll
    for (int ng = 0; ng < 4; ++ng) {
        float bv = bg[ng * 16 + m16];
#pragma unroll
        for (int mg = 0; mg < 2; ++mg) gI[mg][ng] = f32x4{bv, bv, bv, bv};
        if (ng < 2) gH[ng] = f32x4{bv, bv, bv, bv};
    }

    // register double-buffered B-fragments: load s+1 before MFMA(s)
    f16x8 Bc[4];
#pragma unroll
    for (int ng = 0; ng < 4; ++ng)
        Bc[ng] = ld_frag(Wg + (ng * 16 + m16) * 32 + q * 8);

#pragma unroll
    for (int s = 0; s < KG; ++s) {
        f16x8 Bn[4];
        if (s + 1 < KG) {
#pragma unroll
            for (int ng = 0; ng < 4; ++ng)
                Bn[ng] = ld_frag(Wg + ((s + 1) * 64 + ng * 16 + m16) * 32 + q * 8);
        }
        f16x8 AI[2], AH;
        if (L == 0 && s == 9) {
#pragma unroll
            for (int mg = 0; mg < 2; ++mg)
                AI[mg] = x_im2col(sm.xt, wv + 1, mg * 16 + 1 + m16, q);
            AH = x_im2col(sm.xt, hgr, hgc, q);
        } else {
            const int tap = (L == 0) ? s : (s % 9);
            const unsigned short* pl = (L == 1 && s >= 9) ? sm.hs[1] : sm.hs[0];
#pragma unroll
            for (int mg = 0; mg < 2; ++mg)
                AI[mg] = lds_frag_s(pl, (wv + 1 + tap / 3) * 36 + mg * 16 + 1 + m16 + tap % 3, q);
            AH = lds_frag_s(pl, (hgr + tap / 3) * 36 + hgc + tap % 3, q);
        }
#pragma unroll
        for (int mg = 0; mg < 2; ++mg)
#pragma unroll
            for (int ng = 0; ng < 4; ++ng)
                gI[mg][ng] = __builtin_amdgcn_mfma_f32_16x16x32_f16(AI[mg], Bc[ng], gI[mg][ng], 0, 0, 0);
        if (HASH) {
#pragma unroll
            for (int ng = 0; ng < 2; ++ng)
                gH[ng] = __builtin_amdgcn_mfma_f32_16x16x32_f16(AH, Bc[ng], gH[ng], 0, 0, 0);
        }
        if (s + 1 < KG) {
#pragma unroll
            for (int ng = 0; ng < 4; ++ng) Bc[ng] = Bn[ng];
        }
    }

    // gates epilogue. C layout: col(n)=lane&15, row(pixel)=q*4+rg.
    // Interior: r*h -> rh LDS (swizzled); z -> packed f16x2 regs. Halo: r*h only.
    unsigned int zpk[2][4];
#pragma unroll
    for (int mg = 0; mg < 2; ++mg)
#pragma unroll
        for (int rg = 0; rg < 4; ++rg) {
            int gr = wv + 1, gc = mg * 16 + 1 + q * 4 + rg;
            zpk[mg][rg] = (unsigned int)f2h(sigmoid_f(gI[mg][2][rg]))
                        | ((unsigned int)f2h(sigmoid_f(gI[mg][3][rg])) << 16);
#pragma unroll
            for (int ng = 0; ng < 2; ++ng) {
                int n = ng * 16 + m16;
                float rv = sigmoid_f(gI[mg][ng][rg]);
                float hv = h2f(hp[swzus(((gr + 1) * 36 + gc + 1) * 32 + n)]);
                sm.rh[swzus((gr * 34 + gc) * 32 + n)] = f2h(rv * hv);
            }
        }
    if (HASH) {
#pragma unroll
        for (int rg = 0; rg < 4; ++rg) {
            int gr, gc; halo_rc10((wv - 2) * 16 + q * 4 + rg, gr, gc);
#pragma unroll
            for (int ng = 0; ng < 2; ++ng) {
                int n = ng * 16 + m16;
                float rv = sigmoid_f(gH[ng][rg]);
                float hv = h2f(hp[swzus(((gr + 1) * 36 + gc + 1) * 32 + n)]);
                sm.rh[swzus((gr * 34 + gc) * 32 + n)] = f2h(rv * hv);
            }
        }
    }
    __syncthreads();

    // ---- phase 2: candidate conv on interior 8x32 (wave = 1 row, 2 m-tiles)
    f32x4 cacc[2][2];
#pragma unroll
    for (int mg = 0; mg < 2; ++mg)
#pragma unroll
        for (int ng = 0; ng < 2; ++ng) {
            float bv = bc[ng * 16 + m16];
            cacc[mg][ng] = f32x4{bv, bv, bv, bv};
        }
    f16x8 Cc[2];
#pragma unroll
    for (int ng = 0; ng < 2; ++ng)
        Cc[ng] = ld_frag(Wc + (ng * 16 + m16) * 32 + q * 8);
#pragma unroll
    for (int s = 0; s < KC; ++s) {
        f16x8 Cn[2];
        if (s + 1 < KC) {
#pragma unroll
            for (int ng = 0; ng < 2; ++ng)
                Cn[ng] = ld_frag(Wc + ((s + 1) * 32 + ng * 16 + m16) * 32 + q * 8);
        }
        f16x8 A2[2];
        if (L == 0 && s == 9) {
#pragma unroll
            for (int mg = 0; mg < 2; ++mg)
                A2[mg] = x_im2col(sm.xt, wv + 1, mg * 16 + 1 + m16, q);
        } else if (L == 1 && s < 9) {
#pragma unroll
            for (int mg = 0; mg < 2; ++mg)
                A2[mg] = lds_frag_s(sm.hs[0], (wv + 1 + s / 3) * 36 + mg * 16 + m16 + 1 + s % 3, q);
        } else {
            const int tap = (L == 0) ? s : (s - 9);
#pragma unroll
            for (int mg = 0; mg < 2; ++mg)
                A2[mg] = lds_frag_s(sm.rh, (wv + tap / 3) * 34 + mg * 16 + m16 + tap % 3, q);
        }
#pragma unroll
        for (int mg = 0; mg < 2; ++mg)
#pragma unroll
            for (int ng = 0; ng < 2; ++ng)
                cacc[mg][ng] = __builtin_amdgcn_mfma_f32_16x16x32_f16(A2[mg], Cc[ng], cacc[mg][ng], 0, 0, 0);
        if (s + 1 < KC) {
#pragma unroll
            for (int ng = 0; ng < 2; ++ng) Cc[ng] = Cn[ng];
        }
    }

    // ---- update epilogue: h' = (1-z)*h_old + z*tanh(n) ----
    unsigned short hvout[2][2][4];
#pragma unroll
    for (int mg = 0; mg < 2; ++mg)
#pragma unroll
        for (int ng = 0; ng < 2; ++ng)
#pragma unroll
            for (int rg = 0; rg < 4; ++rg) {
                int lcol = mg * 16 + q * 4 + rg;
                int n = ng * 16 + m16;
                float nv = tanh_f(cacc[mg][ng][rg]);
                float zz = h2f((unsigned short)(zpk[mg][rg] >> (ng * 16)));
                float ho = h2f(hp[swzus(((wv + 2) * 36 + lcol + 2) * 32 + n)]);
                float hnew = (1.0f - zz) * ho + zz * nv;
                if (!EMIT) {
                    long psp = (long)(b * PH + R0 + wv + 1) * PH + (C0 + lcol + 1);
                    Hout[psp * 32 + n] = f2h(hnew);
                } else {
                    hvout[mg][ng][rg] = f2h(hnew);
                }
            }

    if (EMIT) {
        // NCHW out via LDS transpose; rh dead after cand -> LINEAR scratch
        // (own write/read pair; independent of the swizzled rh lifetime).
        __syncthreads();
        unsigned short* scr = sm.rh;      // [8 rows][32 cols][32 ch]
#pragma unroll
        for (int mg = 0; mg < 2; ++mg)
#pragma unroll
            for (int ng = 0; ng < 2; ++ng)
#pragma unroll
                for (int rg = 0; rg < 4; ++rg)
                    scr[((wv * 32 + mg * 16 + q * 4 + rg) * 32) + ng * 16 + m16] = hvout[mg][ng][rg];
        __syncthreads();
        const int tid = threadIdx.x;
        const int rowid = tid >> 1, half = tid & 1;
        const int n = rowid >> 3, wr = rowid & 7;
        long obase = ((long)(b * 32 + n) * HH + (R0 + wr)) * HH + C0 + half * 16;
#pragma unroll
        for (int j = 0; j < 16; ++j)
            out[obase + j] = h2f(scr[(wr * 32 + half * 16 + j) * 32 + n]);
    }
}

// ---- solo L0 (t=0): stage h0 + x, compute ----
__global__ __launch_bounds__(512, 4)
void cell_l0(const unsigned short* __restrict__ Hin, unsigned short* __restrict__ Hout,
             const float* __restrict__ seq, int t,
             const unsigned short* __restrict__ Wg, const float* __restrict__ bg,
             const unsigned short* __restrict__ Wc, const float* __restrict__ bc)
{
    __shared__ __align__(16) SmemT sm;
    const int wg = blockIdx.x;
    const int b = wg >> 6, tr = (wg >> 2) & 15, tc = wg & 3;
    const int R0 = tr * 8, C0 = tc * 32;
    stage_x12(sm.xt, seq, b, t, R0, C0);
    stage_plane12(sm.hs[0], Hin, b, R0 - 1, C0 - 1);
    __syncthreads();
    cell_compute<0, 0>(sm, Hout, Wg, bg, Wc, bc, (float*)0, b, R0, C0);
}

// ---- merged pair: z=0 -> L1(t), z=1 -> L0(t+1); both read h0r ----
__global__ __launch_bounds__(512, 4)
void step_pair(const unsigned short* __restrict__ h1r, unsigned short* __restrict__ h1w,
               const unsigned short* __restrict__ h0r, unsigned short* __restrict__ h0w,
               const float* __restrict__ seq, int tnext,
               const unsigned short* __restrict__ WG0, const float* __restrict__ gb0,
               const unsigned short* __restrict__ WC0, const float* __restrict__ cb0,
               const unsigned short* __restrict__ WG1, const float* __restrict__ gb1,
               const unsigned short* __restrict__ WC1, const float* __restrict__ cb1)
{
    __shared__ __align__(16) SmemT sm;
    const int wg = blockIdx.x;
    const int b = wg >> 6, tr = (wg >> 2) & 15, tc = wg & 3;
    const int R0 = tr * 8, C0 = tc * 32;
    if (blockIdx.z == 0) {
        stage_plane12(sm.hs[0], h0r, b, R0 - 1, C0 - 1);   // h0'(t): x-part of L1
        stage_plane12(sm.hs[1], h1r, b, R0 - 1, C0 - 1);   // h1(t): h-old of L1
        __syncthreads();
        cell_compute<1, 0>(sm, h1w, WG1, gb1, WC1, cb1, (float*)0, b, R0, C0);
    } else {
        stage_x12(sm.xt, seq, b, tnext, R0, C0);
        stage_plane12(sm.hs[0], h0r, b, R0 - 1, C0 - 1);   // h-old of L0
        __syncthreads();
        cell_compute<0, 0>(sm, h0w, WG0, gb0, WC0, cb0, (float*)0, b, R0, C0);
    }
}

// ---- final L1(T-1) with inline NCHW emit ----
__global__ __launch_bounds__(512, 4)
void cell_l1_emit(const unsigned short* __restrict__ Hin,
                  const unsigned short* __restrict__ Xin,
                  const unsigned short* __restrict__ Wg, const float* __restrict__ bg,
                  const unsigned short* __restrict__ Wc, const float* __restrict__ bc,
                  float* __restrict__ out)
{
    __shared__ __align__(16) SmemT sm;
    const int wg = blockIdx.x;
    const int b = wg >> 6, tr = (wg >> 2) & 15, tc = wg & 3;
    const int R0 = tr * 8, C0 = tc * 32;
    stage_plane12(sm.hs[0], Xin, b, R0 - 1, C0 - 1);
    stage_plane12(sm.hs[1], Hin, b, R0 - 1, C0 - 1);
    __syncthreads();
    cell_compute<1, 1>(sm, (unsigned short*)0, Wg, bg, Wc, bc, out, b, R0, C0);
}

extern "C" void kernel_launch(void* const* d_in, const int* in_sizes, int n_in,
                              void* d_out, int out_size, void* d_ws, size_t ws_size,
                              hipStream_t stream)
{
    const float* seq = (const float*)d_in[0];
    const float* gw0 = (const float*)d_in[1];
    const float* gb0 = (const float*)d_in[2];
    const float* cw0 = (const float*)d_in[3];
    const float* cb0 = (const float*)d_in[4];
    const float* gw1 = (const float*)d_in[5];
    const float* gb1 = (const float*)d_in[6];
    const float* cw1 = (const float*)d_in[7];
    const float* cb1 = (const float*)d_in[8];
    float* out = (float*)d_out;

    const size_t NSP = (size_t)BB * PH * PH * 32;    // 4,326,400 fp16 per plane

    char* p = (char*)d_ws;
    unsigned short* S0A = (unsigned short*)p; p += NSP * 2;
    unsigned short* S0B = (unsigned short*)p; p += NSP * 2;
    unsigned short* S1A = (unsigned short*)p; p += NSP * 2;
    unsigned short* S1B = (unsigned short*)p; p += NSP * 2;
    unsigned short* WG0 = (unsigned short*)p; p += 20480 * 2;
    unsigned short* WC0 = (unsigned short*)p; p += 10240 * 2;
    unsigned short* WG1 = (unsigned short*)p; p += 36864 * 2;
    unsigned short* WC1 = (unsigned short*)p; p += 18432 * 2;

    // zero all 4 state planes (h=0 init + permanent zero halos), one span
    hipMemsetAsync(S0A, 0, 4 * NSP * 2, stream);

    prep_w<<<(10 * 64 * 32 + 255) / 256, 256, 0, stream>>>(gw0, WG0, 64, 33, 10, 1);
    prep_w<<<(10 * 32 * 32 + 255) / 256, 256, 0, stream>>>(cw0, WC0, 32, 33, 10, 1);
    prep_w<<<(18 * 64 * 32 + 255) / 256, 256, 0, stream>>>(gw1, WG1, 64, 64, 18, 0);
    prep_w<<<(18 * 32 * 32 + 255) / 256, 256, 0, stream>>>(cw1, WC1, 32, 64, 18, 0);

    dim3 grid1(512, 1, 1), grid2(512, 1, 2), block(512);

    // t=0, layer 0: reads S0A (zeros) writes S0B
    cell_l0<<<grid1, block, 0, stream>>>(S0A, S0B, seq, 0, WG0, gb0, WC0, cb0);

    // merged pairs: dispatch k runs L1(t=k) and L0(t=k+1)
    unsigned short *h0r = S0B, *h0w = S0A, *h1r = S1A, *h1w = S1B;
    for (int t = 0; t < TT - 1; ++t) {
        step_pair<<<grid2, block, 0, stream>>>(h1r, h1w, h0r, h0w, seq, t + 1,
                                               WG0, gb0, WC0, cb0,
                                               WG1, gb1, WC1, cb1);
        unsigned short* tmp;
        tmp = h0r; h0r = h0w; h0w = tmp;
        tmp = h1r; h1r = h1w; h1w = tmp;
    }
    // final: L1(15) reads h1r + h0r (h0'(15)), emits NCHW fp32 out
    cell_l1_emit<<<grid1, block, 0, stream>>>(h1r, h0r, WG1, gb1, WC1, cb1, out);
}

// Round 9
// 972.864 us; speedup vs baseline: 1.0330x; 1.0322x over previous
//
#include <hip/hip_runtime.h>

// ConvGRU, fp16 MFMA implicit GEMM.
// R9 = R6 (best verified: 967us) with:
//  - swizzle REVERTED (R8: conflicts 3.56M->1.18M but time 64->66us; conflicts
//    proven non-critical, swizzle VALU cost real: VALUBusy 36->43%)
//  - CHANNEL-PAIR PERMUTATION: prep_w places logical cout 2*m16+ng in physical
//    row ng*16+m16, so each thread's two channels are ADJACENT -> all epilogue
//    h-reads / rh-writes / Hout-stores become paired 4B ops (16 scalar 2B ops
//    -> 8x 4B per site); Hout stores coalesce into 64B runs. State planes end
//    up in standard logical channel order -> conv cin / r*h / emit unchanged.
//  - first-step weight fragments issued BEFORE the staging barrier (their L2
//    latency hides under the global_load_lds drain).
// Schedule: [L0(0)], 15x step_pair[L1(t) || L0(t+1)] (grid.z roles), [L1(15)+emit].
// States fp16 NHWC padded planes [B][130][130][32], 1-px zero halo, ping-pong.
// Stage tile 12x36 (2-px halo) via global_load_lds; clamped rows/cols land in
// the zero halo ring == SAME-pad value. 8x32 out tile per WG, 512 thr.

#define HH 128
#define PH 130
#define HW 16384
#define BB 8
#define TT 16

typedef _Float16 f16x8 __attribute__((ext_vector_type(8)));
typedef float f32x4 __attribute__((ext_vector_type(4)));
typedef unsigned int u32x4 __attribute__((ext_vector_type(4)));

__device__ __forceinline__ unsigned short f2h(float x){
    return __builtin_bit_cast(unsigned short, (_Float16)x);
}
__device__ __forceinline__ float h2f(unsigned short u){
    return (float)__builtin_bit_cast(_Float16, u);
}
__device__ __forceinline__ f16x8 ld_frag(const unsigned short* p){
    u32x4 v = *(const u32x4*)p;
    return __builtin_bit_cast(f16x8, v);
}
__device__ __forceinline__ f16x8 lds_frag_w(const unsigned short* base, int spix, int q){
    u32x4 v = *(const u32x4*)(base + spix * 32 + q * 8);
    return __builtin_bit_cast(f16x8, v);
}
__device__ __forceinline__ float sigmoid_f(float a){ return 1.0f / (1.0f + __expf(-a)); }
__device__ __forceinline__ float tanh_f(float a){ float e2 = __expf(2.0f * a); return 1.0f - 2.0f / (e2 + 1.0f); }
__device__ __forceinline__ unsigned int packh2(float lo, float hi){
    return (unsigned int)f2h(lo) | ((unsigned int)f2h(hi) << 16);
}

// LDS block: 2 stage planes 12x36x32 fp16 + rh 10x34x32 fp16 + x 12x37 fp32
struct SmemT {
    unsigned short hs[2][13824];   // 55,296 B
    unsigned short rh[10880];      // 21,760 B (also out-transpose scratch)
    float xt[444];                 //  1,776 B   => 78,832 B total
};

// halo enumeration for 10x34 gates region: 84 px (rows 0,9 full; rows 1..8
// cols 0,33) as 6 16-px M-tiles; s>83 clamps (benign same-value dups).
__device__ __forceinline__ void halo_rc10(int s, int& gr, int& gc){
    s = s > 83 ? 83 : s;
    if (s < 34)      { gr = 0;            gc = s;      }
    else if (s < 68) { gr = 9;            gc = s - 34; }
    else if (s < 76) { gr = 1 + (s - 68); gc = 0;      }
    else             { gr = 1 + (s - 76); gc = 33;     }
}

// im2col x fragment for gates pixel (gr,gc); xt stride 37, origin R0-2,C0-2
__device__ __forceinline__ f16x8 x_im2col(const float* xt, int gr, int gc, int q){
    f16x8 v;
#pragma unroll
    for (int j = 0; j < 8; ++j) {
        int k = q * 8 + j;
        float f = 0.0f;
        if (k < 9) f = xt[(gr + k / 3) * 37 + gc + k % 3];
        v[j] = (_Float16)f;
    }
    return v;
}

// ---- async DMA staging: 12x36 tile = 432 px * 4 chunks = 1728 = 27*64 ----
__device__ __forceinline__ void stage_plane12(unsigned short* slot,
    const unsigned short* __restrict__ g, int b, int pr0, int pc0)
{
    const int wv = threadIdx.x >> 6, lane = threadIdx.x & 63;
    for (int k = wv; k < 27; k += 8) {
        int chunk = k * 64 + lane;
        int pix = chunk >> 2, part = chunk & 3;
        int r = pix / 36, c = pix - r * 36;
        int pr = pr0 + r; pr = pr < 0 ? 0 : (pr > 129 ? 129 : pr);
        int pc = pc0 + c; pc = pc < 0 ? 0 : (pc > 129 ? 129 : pc);
        const unsigned short* ga = g + ((long)((b * PH + pr) * PH + pc) * 32 + part * 8);
        __builtin_amdgcn_global_load_lds(
            (const __attribute__((address_space(1))) unsigned int*)ga,
            (__attribute__((address_space(3))) unsigned int*)(slot + k * 512),
            16, 0, 0);
    }
}

// stage x(t) 12x37 fp32 tile (scalar loads)
__device__ __forceinline__ void stage_x12(float* xt, const float* __restrict__ seq,
                                          int b, int t, int R0, int C0)
{
    if (threadIdx.x < 444) {
        int p = threadIdx.x;
        int r = p / 37, c = p - r * 37;
        int ir = R0 - 2 + r, ic = C0 - 2 + c;
        float v = 0.0f;
        if (ir >= 0 && ir < HH && ic >= 0 && ic < HH)
            v = seq[((long)b * TT + t) * HW + ir * HH + ic];
        xt[p] = v;
    }
}

// ---- weight prep: [cout][cin_tot][9] fp32 -> [step][cout_phys][32] fp16 ----
// Row permutation: physical row i holds LOGICAL cout
//   lco = (i & ~31) | (2*(i&15) + ((i>>4)&1))
// so MFMA thread (ng,m16) owns logical channels {2*m16+ng} (adjacent pair).
__global__ void prep_w(const float* __restrict__ w, unsigned short* __restrict__ wf,
                       int CO, int CIT, int NSTEP, int xmode)
{
    int idx = blockIdx.x * 256 + threadIdx.x;
    int total = NSTEP * CO * 32;
    if (idx >= total) return;
    int kk = idx & 31;
    int t  = idx >> 5;
    int co = t % CO;
    int s  = t / CO;
    int lco = (co & ~31) | (2 * (co & 15) + ((co >> 4) & 1));
    float v = 0.0f;
    if (xmode && s == NSTEP - 1) {
        if (kk < 9) v = w[(lco * CIT + 0) * 9 + kk];
    } else {
        int tap = s % 9;
        int cin = (s / 9) * 32 + kk + (xmode ? 1 : 0);
        v = w[(lco * CIT + cin) * 9 + tap];
    }
    wf[idx] = f2h(v);
}

// ---- cell compute. Callers ISSUE staging then call; the barrier is inside
// (first-step weight loads issued before it, hiding their L2 latency under
// the DMA drain). L=0: hs[0]=h_old + xt. L=1: hs[0]=x-part, hs[1]=h_old. ----
template<int L, int EMIT>
__device__ __forceinline__ void cell_compute(SmemT& sm,
    unsigned short* __restrict__ Hout,
    const unsigned short* __restrict__ Wg, const float* __restrict__ bg,
    const unsigned short* __restrict__ Wc, const float* __restrict__ bc,
    float* __restrict__ out, int b, int R0, int C0)
{
    constexpr int KG = (L == 0) ? 10 : 18;
    constexpr int KC = (L == 0) ? 10 : 18;

    const int wv = threadIdx.x >> 6, lane = threadIdx.x & 63;
    const int m16 = lane & 15, q = lane >> 4;
    const unsigned short* hp = (L == 0) ? sm.hs[0] : sm.hs[1];

    // pre-barrier weight issue: s=0 gates frags + s=0 cand frags
    f16x8 Bc[4];
#pragma unroll
    for (int ng = 0; ng < 4; ++ng)
        Bc[ng] = ld_frag(Wg + (ng * 16 + m16) * 32 + q * 8);
    f16x8 Cc[2];
#pragma unroll
    for (int ng = 0; ng < 2; ++ng)
        Cc[ng] = ld_frag(Wc + (ng * 16 + m16) * 32 + q * 8);

    __syncthreads();   // drains staging vmcnt(0); weight loads in flight too

    // ---- phase 1: gates conv on 10x34 (16 interior tiles + 6 halo tiles on
    // waves 2..7; halo = r-couts only). Thread's couts: logical 2*m16+ng. ----
    const bool HASH = (wv >= 2);
    int hgr = 0, hgc = 0;
    halo_rc10((wv - 2) * 16 + m16, hgr, hgc);

    f32x4 gI[2][4];
    f32x4 gH[2];
#pragma unroll
    for (int ng = 0; ng < 4; ++ng) {
        float bv = bg[(ng >> 1) * 32 + 2 * m16 + (ng & 1)];
#pragma unroll
        for (int mg = 0; mg < 2; ++mg) gI[mg][ng] = f32x4{bv, bv, bv, bv};
        if (ng < 2) gH[ng] = f32x4{bv, bv, bv, bv};
    }

#pragma unroll
    for (int s = 0; s < KG; ++s) {
        f16x8 Bn[4];
        if (s + 1 < KG) {
#pragma unroll
            for (int ng = 0; ng < 4; ++ng)
                Bn[ng] = ld_frag(Wg + ((s + 1) * 64 + ng * 16 + m16) * 32 + q * 8);
        }
        f16x8 AI[2], AH;
        if (L == 0 && s == 9) {
#pragma unroll
            for (int mg = 0; mg < 2; ++mg)
                AI[mg] = x_im2col(sm.xt, wv + 1, mg * 16 + 1 + m16, q);
            AH = x_im2col(sm.xt, hgr, hgc, q);
        } else {
            const int tap = (L == 0) ? s : (s % 9);
            const unsigned short* pl = (L == 1 && s >= 9) ? sm.hs[1] : sm.hs[0];
#pragma unroll
            for (int mg = 0; mg < 2; ++mg)
                AI[mg] = lds_frag_w(pl, (wv + 1 + tap / 3) * 36 + mg * 16 + 1 + m16 + tap % 3, q);
            AH = lds_frag_w(pl, (hgr + tap / 3) * 36 + hgc + tap % 3, q);
        }
#pragma unroll
        for (int mg = 0; mg < 2; ++mg)
#pragma unroll
            for (int ng = 0; ng < 4; ++ng)
                gI[mg][ng] = __builtin_amdgcn_mfma_f32_16x16x32_f16(AI[mg], Bc[ng], gI[mg][ng], 0, 0, 0);
        if (HASH) {
#pragma unroll
            for (int ng = 0; ng < 2; ++ng)
                gH[ng] = __builtin_amdgcn_mfma_f32_16x16x32_f16(AH, Bc[ng], gH[ng], 0, 0, 0);
        }
        if (s + 1 < KG) {
#pragma unroll
            for (int ng = 0; ng < 4; ++ng) Bc[ng] = Bn[ng];
        }
    }

    // gates epilogue. C layout: col=lane&15 (-> cout pair 2*m16,2*m16+1),
    // row(pixel)=q*4+rg. All h/rh accesses PAIRED 4B at channel 2*m16.
    unsigned int zpk[2][4];
#pragma unroll
    for (int mg = 0; mg < 2; ++mg)
#pragma unroll
        for (int rg = 0; rg < 4; ++rg) {
            int gr = wv + 1, gc = mg * 16 + 1 + q * 4 + rg;
            zpk[mg][rg] = packh2(sigmoid_f(gI[mg][2][rg]), sigmoid_f(gI[mg][3][rg]));
            float rv0 = sigmoid_f(gI[mg][0][rg]);
            float rv1 = sigmoid_f(gI[mg][1][rg]);
            unsigned int hvp = *(const unsigned int*)(hp + ((gr + 1) * 36 + gc + 1) * 32 + 2 * m16);
            float h0 = h2f((unsigned short)hvp), h1 = h2f((unsigned short)(hvp >> 16));
            *(unsigned int*)(sm.rh + (gr * 34 + gc) * 32 + 2 * m16) = packh2(rv0 * h0, rv1 * h1);
        }
    if (HASH) {
#pragma unroll
        for (int rg = 0; rg < 4; ++rg) {
            int gr, gc; halo_rc10((wv - 2) * 16 + q * 4 + rg, gr, gc);
            float rv0 = sigmoid_f(gH[0][rg]);
            float rv1 = sigmoid_f(gH[1][rg]);
            unsigned int hvp = *(const unsigned int*)(hp + ((gr + 1) * 36 + gc + 1) * 32 + 2 * m16);
            float h0 = h2f((unsigned short)hvp), h1 = h2f((unsigned short)(hvp >> 16));
            *(unsigned int*)(sm.rh + (gr * 34 + gc) * 32 + 2 * m16) = packh2(rv0 * h0, rv1 * h1);
        }
    }
    __syncthreads();

    // ---- phase 2: candidate conv on interior 8x32 (wave = 1 row, 2 m-tiles)
    f32x4 cacc[2][2];
#pragma unroll
    for (int mg = 0; mg < 2; ++mg)
#pragma unroll
        for (int ng = 0; ng < 2; ++ng) {
            float bv = bc[2 * m16 + ng];
            cacc[mg][ng] = f32x4{bv, bv, bv, bv};
        }
#pragma unroll
    for (int s = 0; s < KC; ++s) {
        f16x8 Cn[2];
        if (s + 1 < KC) {
#pragma unroll
            for (int ng = 0; ng < 2; ++ng)
                Cn[ng] = ld_frag(Wc + ((s + 1) * 32 + ng * 16 + m16) * 32 + q * 8);
        }
        f16x8 A2[2];
        if (L == 0 && s == 9) {
#pragma unroll
            for (int mg = 0; mg < 2; ++mg)
                A2[mg] = x_im2col(sm.xt, wv + 1, mg * 16 + 1 + m16, q);
        } else if (L == 1 && s < 9) {
#pragma unroll
            for (int mg = 0; mg < 2; ++mg)
                A2[mg] = lds_frag_w(sm.hs[0], (wv + 1 + s / 3) * 36 + mg * 16 + m16 + 1 + s % 3, q);
        } else {
            const int tap = (L == 0) ? s : (s - 9);
#pragma unroll
            for (int mg = 0; mg < 2; ++mg)
                A2[mg] = lds_frag_w(sm.rh, (wv + tap / 3) * 34 + mg * 16 + m16 + tap % 3, q);
        }
#pragma unroll
        for (int mg = 0; mg < 2; ++mg)
#pragma unroll
            for (int ng = 0; ng < 2; ++ng)
                cacc[mg][ng] = __builtin_amdgcn_mfma_f32_16x16x32_f16(A2[mg], Cc[ng], cacc[mg][ng], 0, 0, 0);
        if (s + 1 < KC) {
#pragma unroll
            for (int ng = 0; ng < 2; ++ng) Cc[ng] = Cn[ng];
        }
    }

    // ---- update epilogue: h' = (1-z)*h_old + z*tanh(n); all paired 4B ----
    unsigned int hvout[2][4];
#pragma unroll
    for (int mg = 0; mg < 2; ++mg)
#pragma unroll
        for (int rg = 0; rg < 4; ++rg) {
            int lcol = mg * 16 + q * 4 + rg;
            float nv0 = tanh_f(cacc[mg][0][rg]);
            float nv1 = tanh_f(cacc[mg][1][rg]);
            float zz0 = h2f((unsigned short)zpk[mg][rg]);
            float zz1 = h2f((unsigned short)(zpk[mg][rg] >> 16));
            unsigned int hop = *(const unsigned int*)(hp + ((wv + 2) * 36 + lcol + 2) * 32 + 2 * m16);
            float ho0 = h2f((unsigned short)hop), ho1 = h2f((unsigned short)(hop >> 16));
            float hn0 = (1.0f - zz0) * ho0 + zz0 * nv0;
            float hn1 = (1.0f - zz1) * ho1 + zz1 * nv1;
            if (!EMIT) {
                long psp = (long)(b * PH + R0 + wv + 1) * PH + (C0 + lcol + 1);
                *(unsigned int*)(Hout + psp * 32 + 2 * m16) = packh2(hn0, hn1);
            } else {
                hvout[mg][rg] = packh2(hn0, hn1);
            }
        }

    if (EMIT) {
        // NCHW out via LDS transpose; rh dead after cand -> linear scratch.
        __syncthreads();
        unsigned short* scr = sm.rh;      // [8 rows][32 cols][32 ch]
#pragma unroll
        for (int mg = 0; mg < 2; ++mg)
#pragma unroll
            for (int rg = 0; rg < 4; ++rg)
                *(unsigned int*)(scr + ((wv * 32 + mg * 16 + q * 4 + rg) * 32) + 2 * m16)
                    = hvout[mg][rg];
        __syncthreads();
        const int tid = threadIdx.x;
        const int rowid = tid >> 1, half = tid & 1;
        const int n = rowid >> 3, wr = rowid & 7;   // n = logical channel
        long obase = ((long)(b * 32 + n) * HH + (R0 + wr)) * HH + C0 + half * 16;
#pragma unroll
        for (int j = 0; j < 16; ++j)
            out[obase + j] = h2f(scr[(wr * 32 + half * 16 + j) * 32 + n]);
    }
}

// ---- solo L0 (t=0): stage h0 + x, compute ----
__global__ __launch_bounds__(512, 4)
void cell_l0(const unsigned short* __restrict__ Hin, unsigned short* __restrict__ Hout,
             const float* __restrict__ seq, int t,
             const unsigned short* __restrict__ Wg, const float* __restrict__ bg,
             const unsigned short* __restrict__ Wc, const float* __restrict__ bc)
{
    __shared__ __align__(16) SmemT sm;
    const int wg = blockIdx.x;
    const int b = wg >> 6, tr = (wg >> 2) & 15, tc = wg & 3;
    const int R0 = tr * 8, C0 = tc * 32;
    stage_x12(sm.xt, seq, b, t, R0, C0);
    stage_plane12(sm.hs[0], Hin, b, R0 - 1, C0 - 1);
    cell_compute<0, 0>(sm, Hout, Wg, bg, Wc, bc, (float*)0, b, R0, C0);
}

// ---- merged pair: z=0 -> L1(t), z=1 -> L0(t+1); both read h0r ----
__global__ __launch_bounds__(512, 4)
void step_pair(const unsigned short* __restrict__ h1r, unsigned short* __restrict__ h1w,
               const unsigned short* __restrict__ h0r, unsigned short* __restrict__ h0w,
               const float* __restrict__ seq, int tnext,
               const unsigned short* __restrict__ WG0, const float* __restrict__ gb0,
               const unsigned short* __restrict__ WC0, const float* __restrict__ cb0,
               const unsigned short* __restrict__ WG1, const float* __restrict__ gb1,
               const unsigned short* __restrict__ WC1, const float* __restrict__ cb1)
{
    __shared__ __align__(16) SmemT sm;
    const int wg = blockIdx.x;
    const int b = wg >> 6, tr = (wg >> 2) & 15, tc = wg & 3;
    const int R0 = tr * 8, C0 = tc * 32;
    if (blockIdx.z == 0) {
        stage_plane12(sm.hs[0], h0r, b, R0 - 1, C0 - 1);   // h0'(t): x-part of L1
        stage_plane12(sm.hs[1], h1r, b, R0 - 1, C0 - 1);   // h1(t): h-old of L1
        cell_compute<1, 0>(sm, h1w, WG1, gb1, WC1, cb1, (float*)0, b, R0, C0);
    } else {
        stage_x12(sm.xt, seq, b, tnext, R0, C0);
        stage_plane12(sm.hs[0], h0r, b, R0 - 1, C0 - 1);   // h-old of L0
        cell_compute<0, 0>(sm, h0w, WG0, gb0, WC0, cb0, (float*)0, b, R0, C0);
    }
}

// ---- final L1(T-1) with inline NCHW emit ----
__global__ __launch_bounds__(512, 4)
void cell_l1_emit(const unsigned short* __restrict__ Hin,
                  const unsigned short* __restrict__ Xin,
                  const unsigned short* __restrict__ Wg, const float* __restrict__ bg,
                  const unsigned short* __restrict__ Wc, const float* __restrict__ bc,
                  float* __restrict__ out)
{
    __shared__ __align__(16) SmemT sm;
    const int wg = blockIdx.x;
    const int b = wg >> 6, tr = (wg >> 2) & 15, tc = wg & 3;
    const int R0 = tr * 8, C0 = tc * 32;
    stage_plane12(sm.hs[0], Xin, b, R0 - 1, C0 - 1);
    stage_plane12(sm.hs[1], Hin, b, R0 - 1, C0 - 1);
    cell_compute<1, 1>(sm, (unsigned short*)0, Wg, bg, Wc, bc, out, b, R0, C0);
}

extern "C" void kernel_launch(void* const* d_in, const int* in_sizes, int n_in,
                              void* d_out, int out_size, void* d_ws, size_t ws_size,
                              hipStream_t stream)
{
    const float* seq = (const float*)d_in[0];
    const float* gw0 = (const float*)d_in[1];
    const float* gb0 = (const float*)d_in[2];
    const float* cw0 = (const float*)d_in[3];
    const float* cb0 = (const float*)d_in[4];
    const float* gw1 = (const float*)d_in[5];
    const float* gb1 = (const float*)d_in[6];
    const float* cw1 = (const float*)d_in[7];
    const float* cb1 = (const float*)d_in[8];
    float* out = (float*)d_out;

    const size_t NSP = (size_t)BB * PH * PH * 32;    // 4,326,400 fp16 per plane

    char* p = (char*)d_ws;
    unsigned short* S0A = (unsigned short*)p; p += NSP * 2;
    unsigned short* S0B = (unsigned short*)p; p += NSP * 2;
    unsigned short* S1A = (unsigned short*)p; p += NSP * 2;
    unsigned short* S1B = (unsigned short*)p; p += NSP * 2;
    unsigned short* WG0 = (unsigned short*)p; p += 20480 * 2;
    unsigned short* WC0 = (unsigned short*)p; p += 10240 * 2;
    unsigned short* WG1 = (unsigned short*)p; p += 36864 * 2;
    unsigned short* WC1 = (unsigned short*)p; p += 18432 * 2;

    // zero all 4 state planes (h=0 init + permanent zero halos), one span
    hipMemsetAsync(S0A, 0, 4 * NSP * 2, stream);

    prep_w<<<(10 * 64 * 32 + 255) / 256, 256, 0, stream>>>(gw0, WG0, 64, 33, 10, 1);
    prep_w<<<(10 * 32 * 32 + 255) / 256, 256, 0, stream>>>(cw0, WC0, 32, 33, 10, 1);
    prep_w<<<(18 * 64 * 32 + 255) / 256, 256, 0, stream>>>(gw1, WG1, 64, 64, 18, 0);
    prep_w<<<(18 * 32 * 32 + 255) / 256, 256, 0, stream>>>(cw1, WC1, 32, 64, 18, 0);

    dim3 grid1(512, 1, 1), grid2(512, 1, 2), block(512);

    // t=0, layer 0: reads S0A (zeros) writes S0B
    cell_l0<<<grid1, block, 0, stream>>>(S0A, S0B, seq, 0, WG0, gb0, WC0, cb0);

    // merged pairs: dispatch k runs L1(t=k) and L0(t=k+1)
    unsigned short *h0r = S0B, *h0w = S0A, *h1r = S1A, *h1w = S1B;
    for (int t = 0; t < TT - 1; ++t) {
        step_pair<<<grid2, block, 0, stream>>>(h1r, h1w, h0r, h0w, seq, t + 1,
                                               WG0, gb0, WC0, cb0,
                                               WG1, gb1, WC1, cb1);
        unsigned short* tmp;
        tmp = h0r; h0r = h0w; h0w = tmp;
        tmp = h1r; h1r = h1w; h1w = tmp;
    }
    // final: L1(15) reads h1r + h0r (h0'(15)), emits NCHW fp32 out
    cell_l1_emit<<<grid1, block, 0, stream>>>(h1r, h0r, WG1, gb1, WC1, cb1, out);
}